// Round 7
// baseline (141.998 us; speedup 1.0000x reference)
//
#include <hip/hip_runtime.h>
#include <hip/hip_bf16.h>

#define HW  16384
#define WD  128

#define TS   16            // center tile side
#define HS   18            // halo side
#define HP   (HS * HS)     // 324 halo pixels
#define PRS  20            // padded halo row stride (slots)
#define PLS  360           // plane stride per o4 (ushort4 slots) = 18*20

__device__ __forceinline__ unsigned short f2bf(float f) {
    unsigned int u = __builtin_bit_cast(unsigned int, f);
    u += 0x7FFFu + ((u >> 16) & 1u);          // RNE
    return (unsigned short)(u >> 16);
}
__device__ __forceinline__ float bf2f(unsigned short s) {
    return __builtin_bit_cast(float, (unsigned int)s << 16);
}
__device__ __forceinline__ float ftanh(float v) {
    // tanh(v) = 1 - 2/(exp(2v)+1); exact at +-inf via rcp saturation
    const float e = __expf(2.0f * v);
    return 1.0f - __fdividef(2.0f, e + 1.0f);
}

// ---- fully fused: x -> (t -> mn mask/neighbor) + v + softmax + PV ----------
// grid = (16 bg, 64 tiles): linear id % 8 == g -> per-XCD x locality
__global__ __launch_bounds__(256) void la_fused(
    const float* __restrict__ x,
    const float* __restrict__ w1, const float* __restrict__ b1,
    const float* __restrict__ g1, const float* __restrict__ be1,
    const float* __restrict__ m1, const float* __restrict__ v1,
    const float* __restrict__ w2, const float* __restrict__ b2,
    const float* __restrict__ g2, const float* __restrict__ be2,
    const float* __restrict__ m2, const float* __restrict__ v2,
    const float* __restrict__ wv,
    float* __restrict__ out)
{
    __shared__ ushort4 vt[8 * PLS];            // v tile, bf16x4: 23040 B
    __shared__ float   nbs[PLS];               // neighbor plane fp32: 1440 B

    const int tid  = threadIdx.x;
    const int bg   = blockIdx.x;
    const int tile = blockIdx.y;               // 0..63
    const int b    = bg >> 3, g = bg & 7;
    const int ty0  = (tile >> 3) * TS;
    const int tx0  = (tile & 7) * TS;

    const float* xg  = x + (size_t)(b * 256 + g * 32) * HW;   // group g (for v)
    const float* x0  = x + (size_t)(b * 256) * HW;            // group 0 (for neighbor)
    const float* wvg = wv + g * 1024;

    // neighbor = mn channel g: group 0, conv2 output row o=g, bn2 params ch g
    const float inv_nb = g2[g] * rsqrtf(v2[g] + 1e-5f);
    const float add_nb = be2[g] + (b2[g] - m2[g]) * inv_nb;

    // ---- phase 1: halo -> v (bf16 LDS) + neighbor (fp32 LDS) ----
    for (int hp = tid; hp < HP; hp += 256) {
        const int hy = hp / HS, hx = hp - hy * HS;
        const int iy = ty0 + hy - 1, ix = tx0 + hx - 1;
        const int slot = hy * PRS + hx;
        if (((unsigned)iy < 128u) && ((unsigned)ix < 128u)) {
            const int po = iy * WD + ix;
            float xv[32], xz[32];
#pragma unroll
            for (int c = 0; c < 32; ++c) xv[c] = xg[(size_t)c * HW + po];
#pragma unroll
            for (int c = 0; c < 32; ++c) xz[c] = x0[(size_t)c * HW + po];

            // v = Wv * x_g
#pragma unroll
            for (int o4 = 0; o4 < 8; ++o4) {
                float a0 = 0.f, a1 = 0.f, a2 = 0.f, a3 = 0.f;
                const float* wp = wvg + o4 * 128;
#pragma unroll
                for (int c = 0; c < 32; ++c) {
                    const float xc = xv[c];
                    a0 = fmaf(xc, wp[c],      a0);
                    a1 = fmaf(xc, wp[32 + c], a1);
                    a2 = fmaf(xc, wp[64 + c], a2);
                    a3 = fmaf(xc, wp[96 + c], a3);
                }
                vt[o4 * PLS + slot] = make_ushort4(f2bf(a0), f2bf(a1), f2bf(a2), f2bf(a3));
            }

            // t0 (group 0) + conv2 row g -> neighbor value
            float accn = 0.f;
#pragma unroll
            for (int o = 0; o < 8; ++o) {
                float a = 0.f;
#pragma unroll
                for (int ci = 0; ci < 32; ++ci) a = fmaf(xz[ci], w1[o * 32 + ci], a);
                const float inv = g1[o] * rsqrtf(v1[o] + 1e-5f);
                const float add = be1[o] + (b1[o] - m1[o]) * inv;
                const float t0 = ftanh(fmaf(a, inv, add));
                accn = fmaf(t0, w2[g * 8 + o], accn);
            }
            nbs[slot] = fmaf(accn, inv_nb, add_nb);
        } else {
            const ushort4 z = make_ushort4(0, 0, 0, 0);
#pragma unroll
            for (int o4 = 0; o4 < 8; ++o4) vt[o4 * PLS + slot] = z;
            nbs[slot] = 0.f;       // zero-padded neighbor
        }
    }
    __syncthreads();

    // ---- phase 2: one center pixel per thread ----
    const int cy  = tid >> 4, cx = tid & 15;
    const int iy  = ty0 + cy, ix = tx0 + cx;
    const int pix = iy * WD + ix;

    // mask channels mc0..mc0+8 produced by groups pa (k<ksplit) and pb
    const int mc0    = 8 + 9 * g;
    const int pa     = mc0 / 10;
    const int pb     = (mc0 + 8) / 10;
    const int ksplit = 10 - (mc0 - pa * 10);   // #channels belonging to pa

    float tA[8], tB[8];
    {
        const float* xp  = x  + (size_t)(b * 256 + pa * 32) * HW + pix;
        const float* w1p = w1 + pa * 256;
        float xv[32];
#pragma unroll
        for (int c = 0; c < 32; ++c) xv[c] = xp[(size_t)c * HW];
#pragma unroll
        for (int o = 0; o < 8; ++o) {
            float a = 0.f;
#pragma unroll
            for (int ci = 0; ci < 32; ++ci) a = fmaf(xv[ci], w1p[o * 32 + ci], a);
            const int ch = pa * 8 + o;
            const float inv = g1[ch] * rsqrtf(v1[ch] + 1e-5f);
            const float add = be1[ch] + (b1[ch] - m1[ch]) * inv;
            tA[o] = ftanh(fmaf(a, inv, add));
        }
    }
    if (pb != pa) {
        const float* xp  = x  + (size_t)(b * 256 + pb * 32) * HW + pix;
        const float* w1p = w1 + pb * 256;
        float xv[32];
#pragma unroll
        for (int c = 0; c < 32; ++c) xv[c] = xp[(size_t)c * HW];
#pragma unroll
        for (int o = 0; o < 8; ++o) {
            float a = 0.f;
#pragma unroll
            for (int ci = 0; ci < 32; ++ci) a = fmaf(xv[ci], w1p[o * 32 + ci], a);
            const int ch = pb * 8 + o;
            const float inv = g1[ch] * rsqrtf(v1[ch] + 1e-5f);
            const float add = be1[ch] + (b1[ch] - m1[ch]) * inv;
            tB[o] = ftanh(fmaf(a, inv, add));
        }
    } else {
#pragma unroll
        for (int o = 0; o < 8; ++o) tB[o] = tA[o];
    }

    float lg[9];
    float mx = -1e30f;
#pragma unroll
    for (int k = 0; k < 9; ++k) {
        const int mc = mc0 + k;                 // mn channel (uniform)
        const int p  = (k < ksplit) ? pa : pb;
        const int o  = mc - p * 10;
        const float* w2p = w2 + p * 80 + o * 8;
        float a = 0.f;
#pragma unroll
        for (int i = 0; i < 8; ++i) {
            const float ti = (k < ksplit) ? tA[i] : tB[i];
            a = fmaf(ti, w2p[i], a);
        }
        const float inv = g2[mc] * rsqrtf(v2[mc] + 1e-5f);
        const float add = be2[mc] + (b2[mc] - m2[mc]) * inv;
        const float mask = fmaf(a, inv, add);
        lg[k] = mask + nbs[(cy + k / 3) * PRS + (cx + k % 3)];
        mx = fmaxf(mx, lg[k]);
    }
    float s = 0.f;
#pragma unroll
    for (int k = 0; k < 9; ++k) { lg[k] = __expf(lg[k] - mx); s += lg[k]; }
    const float rs = 1.f / s;
#pragma unroll
    for (int k = 0; k < 9; ++k) lg[k] *= rs;   // OOB taps hit v==0 in LDS

    float* og = out + (size_t)(b * 256 + g * 32) * HW + pix;
#pragma unroll 2
    for (int o4 = 0; o4 < 8; ++o4) {
        const ushort4* vp = vt + o4 * PLS;
        float a0 = 0.f, a1 = 0.f, a2 = 0.f, a3 = 0.f;
#pragma unroll
        for (int k = 0; k < 9; ++k) {
            const int slot = (cy + k / 3) * PRS + (cx + k % 3);
            const ushort4 vv = vp[slot];
            a0 = fmaf(lg[k], bf2f(vv.x), a0);
            a1 = fmaf(lg[k], bf2f(vv.y), a1);
            a2 = fmaf(lg[k], bf2f(vv.z), a2);
            a3 = fmaf(lg[k], bf2f(vv.w), a3);
        }
        __builtin_nontemporal_store(a0, og + (size_t)(o4 * 4 + 0) * HW);
        __builtin_nontemporal_store(a1, og + (size_t)(o4 * 4 + 1) * HW);
        __builtin_nontemporal_store(a2, og + (size_t)(o4 * 4 + 2) * HW);
        __builtin_nontemporal_store(a3, og + (size_t)(o4 * 4 + 3) * HW);
    }
}

extern "C" void kernel_launch(void* const* d_in, const int* in_sizes, int n_in,
                              void* d_out, int out_size, void* d_ws, size_t ws_size,
                              hipStream_t stream)
{
    const float* x   = (const float*)d_in[0];
    const float* w1  = (const float*)d_in[1];
    const float* b1  = (const float*)d_in[2];
    const float* g1  = (const float*)d_in[3];
    const float* be1 = (const float*)d_in[4];
    const float* m1  = (const float*)d_in[5];
    const float* v1  = (const float*)d_in[6];
    const float* w2  = (const float*)d_in[7];
    const float* b2  = (const float*)d_in[8];
    const float* g2  = (const float*)d_in[9];
    const float* be2 = (const float*)d_in[10];
    const float* m2  = (const float*)d_in[11];
    const float* v2  = (const float*)d_in[12];
    const float* wv  = (const float*)d_in[13];

    float* out = (float*)d_out;

    dim3 blk(256);
    dim3 grd(16, 64);              // (bg, tile): id%8==g -> XCD locality

    hipLaunchKernelGGL(la_fused, grd, blk, 0, stream,
                       x, w1, b1, g1, be1, m1, v1, w2, b2, g2, be2, m2, v2, wv,
                       out);
}